// Round 5
// baseline (434.209 us; speedup 1.0000x reference)
//
#include <hip/hip_runtime.h>

typedef __bf16 bf16;
typedef __bf16 bf16x8 __attribute__((ext_vector_type(8)));
typedef float f32x4 __attribute__((ext_vector_type(4)));

constexpr int BATCH = 32;
constexpr int SEQ   = 1024;
constexpr int CDIM  = 768;
constexpr int ROWS  = BATCH * SEQ;   // 32768
constexpr int QKVC  = 3 * CDIM;      // 2304

// ---- workspace layout (bytes), ~273.3 MB total ----
constexpr size_t oWqT = 0;                                    // bf16 WqkvT [2304][768]
constexpr size_t oWpT = oWqT + (size_t)QKVC * CDIM * 2;       // bf16 WprojT [768][768]
constexpr size_t oQKV = oWpT + (size_t)CDIM * CDIM * 2;       // bf16 qkv [32768][2304]
constexpr size_t oS   = oQKV + (size_t)ROWS * QKVC * 2;       // bf16 S [32][1024][1024]
constexpr size_t oVT  = oS   + (size_t)BATCH * SEQ * SEQ * 2; // bf16 VT [32][768][1024]
constexpr size_t oInv = oVT  + (size_t)BATCH * CDIM * SEQ * 2;// f32 invsum [32768]
constexpr size_t oAO  = oQKV; // attn_out aliases qkv (dead after vtrans + QK^T)
constexpr size_t oXB  = oS;   // bf16(x) aliases S (dead before QK^T writes S)
constexpr size_t oPart= oWqT; // f32 partial[32768][4] aliases WqT (dead after qkv GEMM)

__device__ __forceinline__ void gld_lds16(const void* g, void* l) {
  __builtin_amdgcn_global_load_lds(
      (const __attribute__((address_space(1))) unsigned int*)g,
      (__attribute__((address_space(3))) unsigned int*)l,
      16, 0, 0);
}

// ---------- x fp32 -> bf16 ----------
__global__ __launch_bounds__(256) void f2b_kernel(const float* __restrict__ x,
                                                  bf16* __restrict__ y) {
  int i = blockIdx.x * blockDim.x + threadIdx.x;
  const float* p = x + (size_t)i * 8;
  float4 a = *(const float4*)p;
  float4 b = *(const float4*)(p + 4);
  bf16x8 o;
  o[0]=(bf16)a.x; o[1]=(bf16)a.y; o[2]=(bf16)a.z; o[3]=(bf16)a.w;
  o[4]=(bf16)b.x; o[5]=(bf16)b.y; o[6]=(bf16)b.z; o[7]=(bf16)b.w;
  *(bf16x8*)(y + (size_t)i * 8) = o;
}

// ---------- weight transpose+convert (tiled): T[n][k] = bf16(W[k][n]) ----------
__global__ __launch_bounds__(256) void wt_kernel(const float* __restrict__ W,
                                                 bf16* __restrict__ T, int N) {
  __shared__ float t[32][33];
  int k0 = blockIdx.x * 32, n0 = blockIdx.y * 32;
  int tx = threadIdx.x & 31, ty = threadIdx.x >> 5; // 32 x 8
  #pragma unroll
  for (int i = 0; i < 4; ++i)
    t[ty + i * 8][tx] = W[(size_t)(k0 + ty + i * 8) * N + n0 + tx];
  __syncthreads();
  #pragma unroll
  for (int i = 0; i < 4; ++i)
    T[(size_t)(n0 + ty + i * 8) * 768 + k0 + tx] = (bf16)t[tx][ty + i * 8];
}

// ---------- V transpose: VT[b][c][m] = qkv[b*1024+m][1536+c] ----------
__global__ __launch_bounds__(256) void vtrans_kernel(const bf16* __restrict__ qkv,
                                                     bf16* __restrict__ vt) {
  __shared__ bf16 t[64][68];
  int b = blockIdx.z, m0 = blockIdx.x * 64, c0 = blockIdx.y * 64;
  int tid = threadIdx.x;
  #pragma unroll
  for (int it = 0; it < 2; ++it) {
    int m = it * 32 + (tid >> 3);
    int c = (tid & 7) * 8;
    bf16x8 v = *(const bf16x8*)(qkv + ((size_t)b * SEQ + m0 + m) * QKVC + 2 * CDIM + c0 + c);
    #pragma unroll
    for (int i = 0; i < 8; ++i) t[c + i][m] = v[i];
  }
  __syncthreads();
  #pragma unroll
  for (int it = 0; it < 2; ++it) {
    int c = it * 32 + (tid >> 3);
    int m = (tid & 7) * 8;
    bf16x8 o;
    #pragma unroll
    for (int i = 0; i < 8; ++i) o[i] = t[c][m + i];
    *(bf16x8*)(vt + ((size_t)b * CDIM + c0 + c) * SEQ + m0 + m) = o;
  }
}

// ---------- finish: inv[row] = 1 / sum_nt partial[row][nt] ----------
__global__ __launch_bounds__(256) void finish_kernel(const float* __restrict__ partial,
                                                     float* __restrict__ inv) {
  int i = blockIdx.x * 256 + threadIdx.x;
  float4 p = *(const float4*)(partial + (size_t)i * 4);
  inv[i] = 1.0f / (p.x + p.y + p.z + p.w);
}

// ================= 256x256 8-wave phased NT GEMM, counted-vmcnt (T4) =============
// C[z][m][n] = scale*rowScale[z][m]*sum_k A[z][m][k]*B[z][n][k] + bias[n]
// BK=64, LDS 2x(A 256x64 + B 256x64) bf16 = 128 KiB double buffer.
// K-loop: {issue 8 gld_lds for t+1 -> vmcnt(8) [own tile-t loads done; t+1's 8
// stay in flight] -> s_barrier C [tile t published] -> 4 phases {ds_read;
// lgkmcnt(0)+sched_barrier; setprio 16xMFMA} -> s_barrier D [licenses next
// overwrite of buf[cur]]}. vmcnt is per-wave: each wave bounds its OWN loads
// before C; C publishes all waves' (round-3 lesson).
// T2 swizzle: linear LDS dest, inverse-swizzled GLOBAL chunk c8^(r&7),
// swizzled ds_read byte kb^((row&7)<<4)  (rule 21: both-sides-or-neither).
// FUSE_EXP (QK^T): epilogue stores bf16(exp(acc*scale)) and reduces per-row
// sums (shfl_xor over 16 lanes, cross-wave via LDS, deterministic) ->
// partial[grow][nt].

#define LOADA(mh_) do {                                                          \
  _Pragma("unroll")                                                              \
  for (int i_ = 0; i_ < 4; ++i_) {                                               \
    const int row_ = wm * 128 + ((mh_) * 4 + i_) * 16 + lr;                      \
    const char* rb_ = (const char*)Acur + row_ * 128;                            \
    af[i_][0] = *(const bf16x8*)(rb_ + ((0  + kb0) ^ swz));                      \
    af[i_][1] = *(const bf16x8*)(rb_ + ((64 + kb0) ^ swz));                      \
  }                                                                              \
} while (0)

#define PHASE(mh_, nh_, LA_) do {                                                \
  if (LA_) LOADA(mh_);                                                           \
  bf16x8 bfr[2][2];                                                              \
  _Pragma("unroll")                                                              \
  for (int j_ = 0; j_ < 2; ++j_) {                                               \
    const int row_ = wn * 64 + ((nh_) * 2 + j_) * 16 + lr;                       \
    const char* rb_ = (const char*)Bcur + row_ * 128;                            \
    bfr[j_][0] = *(const bf16x8*)(rb_ + ((0  + kb0) ^ swz));                     \
    bfr[j_][1] = *(const bf16x8*)(rb_ + ((64 + kb0) ^ swz));                     \
  }                                                                              \
  asm volatile("s_waitcnt lgkmcnt(0)" ::: "memory");                             \
  __builtin_amdgcn_sched_barrier(0);                                             \
  __builtin_amdgcn_s_setprio(1);                                                 \
  _Pragma("unroll")                                                              \
  for (int ks_ = 0; ks_ < 2; ++ks_)                                              \
    _Pragma("unroll")                                                            \
    for (int i_ = 0; i_ < 4; ++i_)                                               \
      _Pragma("unroll")                                                          \
      for (int j_ = 0; j_ < 2; ++j_)                                             \
        acc[(mh_) * 4 + i_][(nh_) * 2 + j_] =                                    \
            __builtin_amdgcn_mfma_f32_16x16x32_bf16(af[i_][ks_], bfr[j_][ks_],   \
                acc[(mh_) * 4 + i_][(nh_) * 2 + j_], 0, 0, 0);                   \
  __builtin_amdgcn_s_setprio(0);                                                 \
} while (0)

template<bool OUT_BF16, bool HAS_BIAS, bool ROW_SCALE, bool FUSE_EXP>
__global__ __launch_bounds__(512, 2) void gemm256(
    const bf16* __restrict__ Ap, const bf16* __restrict__ Bp, void* __restrict__ Cp,
    int K, int lda, int ldb, int ldc, int ntm, int ntn,
    long sA, long sB, long sC,
    float scale, const float* __restrict__ rowScale, long sRS,
    const float* __restrict__ bias, float* __restrict__ partial)
{
  __shared__ __align__(16) bf16 As[2][256 * 64];
  __shared__ __align__(16) bf16 Bs[2][256 * 64];
  const int tid  = threadIdx.x;
  const int lane = tid & 63;
  const int wv   = tid >> 6;      // 0..7
  const int wm   = wv >> 2;       // 0..1  (128-row half)
  const int wn   = wv & 3;        // 0..3  (64-col strip)

  // XCD-chunked bijective swizzle (grid always a multiple of 8 here)
  const int total = (int)gridDim.x;
  const int chunk = total >> 3;
  const int bid   = (int)blockIdx.x;
  int sbid = (bid & 7) * chunk + (bid >> 3);
  const int pb = ntm * ntn;
  const int z  = sbid / pb;  sbid -= z * pb;
  const int mt = sbid / ntn;
  const int nt = sbid - mt * ntn;
  const int m0 = mt * 256, n0 = nt * 256;

  const bf16* A = Ap + (size_t)z * sA;
  const bf16* B = Bp + (size_t)z * sB;

  // staging map: row sr (0..63 per segment), chunk sc8; global chunk pre-swizzled
  const int sr  = tid >> 3;
  const int sc8 = tid & 7;
  const int gch = sc8 ^ (sr & 7);
  const bf16* Ast = A + (size_t)(m0 + sr) * lda + gch * 8;
  const bf16* Bst = B + (size_t)(n0 + sr) * ldb + gch * 8;

  const int lr  = lane & 15;
  const int swz = (lane & 7) << 4;
  const int kb0 = (lane >> 4) * 16;

  f32x4 acc[8][4] = {};

  // prologue: stage K-tile 0 only (no wait/barrier needed — loop handles it)
  #pragma unroll
  for (int p = 0; p < 4; ++p) {
    gld_lds16(Ast + (size_t)(p * 64) * lda, &As[0][p * 4096 + wv * 512]);
    gld_lds16(Bst + (size_t)(p * 64) * ldb, &Bs[0][p * 4096 + wv * 512]);
  }

  const int nkt = K >> 6;
  for (int t = 0; t < nkt; ++t) {
    const int cur = t & 1;
    const bf16* Acur = As[cur];
    const bf16* Bcur = Bs[cur];
    bf16* Asn = As[cur ^ 1];
    bf16* Bsn = Bs[cur ^ 1];
    if (t + 1 < nkt) {
      const int ktn = (t + 1) << 6;
      #pragma unroll
      for (int p = 0; p < 4; ++p) {   // issue t+1 BEFORE waiting for t (T4)
        gld_lds16(Ast + (size_t)(p * 64) * lda + ktn, Asn + p * 4096 + wv * 512);
        gld_lds16(Bst + (size_t)(p * 64) * ldb + ktn, Bsn + p * 4096 + wv * 512);
      }
      asm volatile("s_waitcnt vmcnt(8)" ::: "memory");  // own tile-t loads done
    } else {
      asm volatile("s_waitcnt vmcnt(0)" ::: "memory");
    }
    __builtin_amdgcn_s_barrier();          // C: tile t published by all waves
    __builtin_amdgcn_sched_barrier(0);
    bf16x8 af[4][2];
    PHASE(0, 0, 1);
    PHASE(0, 1, 0);
    PHASE(1, 1, 1);
    PHASE(1, 0, 0);
    __builtin_amdgcn_s_barrier();          // D: all reads of buf[cur] done
    __builtin_amdgcn_sched_barrier(0);
  }

  // epilogue: C/D layout col=lane&15, row=(lane>>4)*4+reg (m89-verified)
  if (FUSE_EXP) {
    float rs[8][4];
    #pragma unroll
    for (int mf = 0; mf < 8; ++mf)
      #pragma unroll
      for (int r = 0; r < 4; ++r) rs[mf][r] = 0.f;
    #pragma unroll
    for (int mf = 0; mf < 8; ++mf)
      #pragma unroll
      for (int nf = 0; nf < 4; ++nf)
        #pragma unroll
        for (int r = 0; r < 4; ++r) {
          int gm = m0 + wm * 128 + mf * 16 + ((lane >> 4) * 4 + r);
          int gn = n0 + wn * 64 + nf * 16 + (lane & 15);
          float e = __expf(acc[mf][nf][r] * scale);
          ((bf16*)Cp)[(size_t)z * sC + (size_t)gm * ldc + gn] = (bf16)e;
          rs[mf][r] += e;
        }
    float* sl = (float*)As;  // [4 strips][256 rows], LDS free after barrier D
    #pragma unroll
    for (int mf = 0; mf < 8; ++mf)
      #pragma unroll
      for (int r = 0; r < 4; ++r) {
        float s = rs[mf][r];
        s += __shfl_xor(s, 1); s += __shfl_xor(s, 2);
        s += __shfl_xor(s, 4); s += __shfl_xor(s, 8);
        if ((lane & 15) == 0)
          sl[wn * 256 + wm * 128 + mf * 16 + (lane >> 4) * 4 + r] = s;
      }
    __syncthreads();
    if (tid < 256) {
      float s = sl[tid] + sl[256 + tid] + sl[512 + tid] + sl[768 + tid];
      partial[((size_t)z * SEQ + m0 + tid) * 4 + nt] = s;
    }
  } else {
    #pragma unroll
    for (int mf = 0; mf < 8; ++mf) {
      #pragma unroll
      for (int nf = 0; nf < 4; ++nf) {
        #pragma unroll
        for (int r = 0; r < 4; ++r) {
          int gm = m0 + wm * 128 + mf * 16 + ((lane >> 4) * 4 + r);
          int gn = n0 + wn * 64 + nf * 16 + (lane & 15);
          float v = acc[mf][nf][r] * scale;
          if (ROW_SCALE) v *= rowScale[(size_t)z * sRS + gm];
          if (HAS_BIAS)  v += bias[gn];
          if (OUT_BF16) ((bf16*)Cp)[(size_t)z * sC + (size_t)gm * ldc + gn] = (bf16)v;
          else          ((float*)Cp)[(size_t)z * sC + (size_t)gm * ldc + gn] = v;
        }
      }
    }
  }
}

extern "C" void kernel_launch(void* const* d_in, const int* in_sizes, int n_in,
                              void* d_out, int out_size, void* d_ws, size_t ws_size,
                              hipStream_t stream) {
  const float* x     = (const float*)d_in[0];
  const float* Wqkv  = (const float*)d_in[1];
  const float* bqkv  = (const float*)d_in[2];
  const float* Wproj = (const float*)d_in[3];
  const float* bproj = (const float*)d_in[4];
  float* out = (float*)d_out;
  char*  ws  = (char*)d_ws;

  bf16*  WqT = (bf16*)(ws + oWqT);
  bf16*  WpT = (bf16*)(ws + oWpT);
  bf16*  qkv = (bf16*)(ws + oQKV);
  bf16*  S   = (bf16*)(ws + oS);
  bf16*  VT  = (bf16*)(ws + oVT);
  float* inv = (float*)(ws + oInv);
  bf16*  AO  = (bf16*)(ws + oAO);
  bf16*  xb  = (bf16*)(ws + oXB);
  float* part= (float*)(ws + oPart);

  const float qk_scale = 1.0f / sqrtf((float)CDIM);

  // 1. conversions / transposes
  f2b_kernel<<<ROWS * CDIM / 8 / 256, 256, 0, stream>>>(x, xb);
  wt_kernel<<<dim3(768 / 32, QKVC / 32), 256, 0, stream>>>(Wqkv, WqT, QKVC);
  wt_kernel<<<dim3(768 / 32, CDIM / 32), 256, 0, stream>>>(Wproj, WpT, CDIM);

  // 2. qkv = xb @ WqT^T + b_qkv   [32768 x 2304]
  gemm256<true, true, false, false><<<(ROWS / 256) * (QKVC / 256), 512, 0, stream>>>(
      xb, WqT, qkv, CDIM, CDIM, CDIM, QKVC, ROWS / 256, QKVC / 256,
      0, 0, 0, 1.0f, nullptr, 0, bqkv, nullptr);

  // 3. VT[b][c][m] = v
  vtrans_kernel<<<dim3(SEQ / 64, CDIM / 64, BATCH), 256, 0, stream>>>(qkv, VT);

  // 4. S = exp(q @ k^T * scale), fused row-partial sums (overwrites xb & WqT — both dead)
  gemm256<true, false, false, true><<<BATCH * (SEQ / 256) * (SEQ / 256), 512, 0, stream>>>(
      qkv, qkv + CDIM, S, CDIM, QKVC, QKVC, SEQ, SEQ / 256, SEQ / 256,
      (long)SEQ * QKVC, (long)SEQ * QKVC, (long)SEQ * SEQ, qk_scale, nullptr, 0, nullptr, part);

  // 5. inv = 1/rowsum  (sums the 4 n-tile partials)
  finish_kernel<<<ROWS / 256, 256, 0, stream>>>(part, inv);

  // 6. attn_out = (expS @ VT^T) * inv[row]   [32 x 1024 x 768]
  gemm256<true, false, true, false><<<BATCH * (SEQ / 256) * (CDIM / 256), 512, 0, stream>>>(
      S, VT, AO, SEQ, SEQ, SEQ, CDIM, SEQ / 256, CDIM / 256,
      (long)SEQ * SEQ, (long)CDIM * SEQ, (long)SEQ * CDIM, 1.0f, inv, SEQ, nullptr, nullptr);

  // 7. out = attn_out @ WpT^T + b_proj   [32768 x 768], fp32
  gemm256<false, true, false, false><<<(ROWS / 256) * (CDIM / 256), 512, 0, stream>>>(
      AO, WpT, out, CDIM, CDIM, CDIM, CDIM, ROWS / 256, CDIM / 256,
      0, 0, 0, 1.0f, nullptr, 0, bproj, nullptr);
}

// Round 6
// 358.169 us; speedup vs baseline: 1.2123x; 1.2123x over previous
//
#include <hip/hip_runtime.h>

typedef __bf16 bf16;
typedef __bf16 bf16x4 __attribute__((ext_vector_type(4)));
typedef __bf16 bf16x8 __attribute__((ext_vector_type(8)));
typedef float f32x4 __attribute__((ext_vector_type(4)));

constexpr int BATCH = 32;
constexpr int SEQ   = 1024;
constexpr int CDIM  = 768;
constexpr int ROWS  = BATCH * SEQ;   // 32768
constexpr int QKVC  = 3 * CDIM;      // 2304

// ---- workspace layout (bytes), ~273.3 MB total ----
constexpr size_t oWqT = 0;                                    // bf16 WqkvT [2304][768]
constexpr size_t oWpT = oWqT + (size_t)QKVC * CDIM * 2;       // bf16 WprojT [768][768]
constexpr size_t oQKV = oWpT + (size_t)CDIM * CDIM * 2;       // bf16 qkv [32768][2304]
constexpr size_t oS   = oQKV + (size_t)ROWS * QKVC * 2;       // bf16 S [32][1024][1024]
constexpr size_t oVT  = oS   + (size_t)BATCH * SEQ * SEQ * 2; // bf16 VT [32][768][1024]
constexpr size_t oInv = oVT  + (size_t)BATCH * CDIM * SEQ * 2;// f32 invsum [32768]
constexpr size_t oAO  = oQKV; // attn_out aliases qkv (q/k dead after QK^T)
constexpr size_t oXB  = oS;   // bf16(x) aliases S (dead before QK^T writes S)
constexpr size_t oPart= oWqT; // f32 partial[32768][4] aliases WqT (dead after qkv GEMM)

__device__ __forceinline__ void gld_lds16(const void* g, void* l) {
  __builtin_amdgcn_global_load_lds(
      (const __attribute__((address_space(1))) unsigned int*)g,
      (__attribute__((address_space(3))) unsigned int*)l,
      16, 0, 0);
}

// ---------- x fp32 -> bf16 ----------
__global__ __launch_bounds__(256) void f2b_kernel(const float* __restrict__ x,
                                                  bf16* __restrict__ y) {
  int i = blockIdx.x * blockDim.x + threadIdx.x;
  const float* p = x + (size_t)i * 8;
  float4 a = *(const float4*)p;
  float4 b = *(const float4*)(p + 4);
  bf16x8 o;
  o[0]=(bf16)a.x; o[1]=(bf16)a.y; o[2]=(bf16)a.z; o[3]=(bf16)a.w;
  o[4]=(bf16)b.x; o[5]=(bf16)b.y; o[6]=(bf16)b.z; o[7]=(bf16)b.w;
  *(bf16x8*)(y + (size_t)i * 8) = o;
}

// ---------- weight transpose+convert (tiled): T[n][k] = bf16(W[k][n]) ----------
__global__ __launch_bounds__(256) void wt_kernel(const float* __restrict__ W,
                                                 bf16* __restrict__ T, int N) {
  __shared__ float t[32][33];
  int k0 = blockIdx.x * 32, n0 = blockIdx.y * 32;
  int tx = threadIdx.x & 31, ty = threadIdx.x >> 5; // 32 x 8
  #pragma unroll
  for (int i = 0; i < 4; ++i)
    t[ty + i * 8][tx] = W[(size_t)(k0 + ty + i * 8) * N + n0 + tx];
  __syncthreads();
  #pragma unroll
  for (int i = 0; i < 4; ++i)
    T[(size_t)(n0 + ty + i * 8) * 768 + k0 + tx] = (bf16)t[tx][ty + i * 8];
}

// ---------- finish: inv[row] = 1 / sum_nt partial[row][nt] ----------
__global__ __launch_bounds__(256) void finish_kernel(const float* __restrict__ partial,
                                                     float* __restrict__ inv) {
  int i = blockIdx.x * 256 + threadIdx.x;
  float4 p = *(const float4*)(partial + (size_t)i * 4);
  inv[i] = 1.0f / (p.x + p.y + p.z + p.w);
}

// ================= 256x256 8-wave phased NT GEMM (round-4 schedule) ==============
// C[z][m][n] = scale*rowScale[z][m]*sum_k A[z][m][k]*B[z][n][k] + bias[n]
// BK=64, LDS 2x(A 256x64 + B 256x64) bf16 = 128 KiB double buffer.
// Per K-tile: 4 phases {ds_read frags; (phases 0-1: issue 4 gld_lds for t+1);
// lgkmcnt(0)+sched_barrier; setprio 16xMFMA}; then vmcnt(0) (own stages done,
// per-wave counter — round-3 lesson) THEN s_barrier (publishes all).
// T2 swizzle: linear LDS dest, inverse-swizzled GLOBAL chunk c8^(r&7),
// swizzled ds_read byte kb^((row&7)<<4)  (rule 21: both-sides-or-neither).
// FUSE_EXP (QK^T): epilogue stores bf16(exp(acc*scale)), per-row partial sums.
// TR_V (qkv GEMM): blocks with nt>=6 (V columns) write VT transposed via LDS.

#define LOADA(mh_) do {                                                          \
  _Pragma("unroll")                                                              \
  for (int i_ = 0; i_ < 4; ++i_) {                                               \
    const int row_ = wm * 128 + ((mh_) * 4 + i_) * 16 + lr;                      \
    const char* rb_ = (const char*)Acur + row_ * 128;                            \
    af[i_][0] = *(const bf16x8*)(rb_ + ((0  + kb0) ^ swz));                      \
    af[i_][1] = *(const bf16x8*)(rb_ + ((64 + kb0) ^ swz));                      \
  }                                                                              \
} while (0)

#define STAGE2(sp0_, sp1_) do {                                                  \
  if (t + 1 < nkt) {                                                             \
    gld_lds16(Ast + (size_t)((sp0_) * 64) * lda + ktn, Asn + (sp0_) * 4096 + wv * 512); \
    gld_lds16(Bst + (size_t)((sp0_) * 64) * ldb + ktn, Bsn + (sp0_) * 4096 + wv * 512); \
    gld_lds16(Ast + (size_t)((sp1_) * 64) * lda + ktn, Asn + (sp1_) * 4096 + wv * 512); \
    gld_lds16(Bst + (size_t)((sp1_) * 64) * ldb + ktn, Bsn + (sp1_) * 4096 + wv * 512); \
  }                                                                              \
} while (0)

#define PHASE(mh_, nh_, LA_, STG_) do {                                          \
  if (LA_) LOADA(mh_);                                                           \
  bf16x8 bfr[2][2];                                                              \
  _Pragma("unroll")                                                              \
  for (int j_ = 0; j_ < 2; ++j_) {                                               \
    const int row_ = wn * 64 + ((nh_) * 2 + j_) * 16 + lr;                       \
    const char* rb_ = (const char*)Bcur + row_ * 128;                            \
    bfr[j_][0] = *(const bf16x8*)(rb_ + ((0  + kb0) ^ swz));                     \
    bfr[j_][1] = *(const bf16x8*)(rb_ + ((64 + kb0) ^ swz));                     \
  }                                                                              \
  STG_;                                                                          \
  asm volatile("s_waitcnt lgkmcnt(0)" ::: "memory");                             \
  __builtin_amdgcn_sched_barrier(0);                                             \
  __builtin_amdgcn_s_setprio(1);                                                 \
  _Pragma("unroll")                                                              \
  for (int ks_ = 0; ks_ < 2; ++ks_)                                              \
    _Pragma("unroll")                                                            \
    for (int i_ = 0; i_ < 4; ++i_)                                               \
      _Pragma("unroll")                                                          \
      for (int j_ = 0; j_ < 2; ++j_)                                             \
        acc[(mh_) * 4 + i_][(nh_) * 2 + j_] =                                    \
            __builtin_amdgcn_mfma_f32_16x16x32_bf16(af[i_][ks_], bfr[j_][ks_],   \
                acc[(mh_) * 4 + i_][(nh_) * 2 + j_], 0, 0, 0);                   \
  __builtin_amdgcn_s_setprio(0);                                                 \
} while (0)

template<bool OUT_BF16, bool HAS_BIAS, bool ROW_SCALE, bool FUSE_EXP, bool TR_V>
__global__ __launch_bounds__(512, 2) void gemm256(
    const bf16* __restrict__ Ap, const bf16* __restrict__ Bp, void* __restrict__ Cp,
    int K, int lda, int ldb, int ldc, int ntm, int ntn,
    long sA, long sB, long sC,
    float scale, const float* __restrict__ rowScale, long sRS,
    const float* __restrict__ bias, float* __restrict__ partial,
    bf16* __restrict__ vtout)
{
  __shared__ __align__(16) bf16 LDSB[4][256 * 64]; // [A0,A1,B0,B1], 128 KiB
  const int tid  = threadIdx.x;
  const int lane = tid & 63;
  const int wv   = tid >> 6;      // 0..7
  const int wm   = wv >> 2;       // 0..1  (128-row half)
  const int wn   = wv & 3;        // 0..3  (64-col strip)

  // XCD-chunked bijective swizzle (grid always a multiple of 8 here)
  const int total = (int)gridDim.x;
  const int chunk = total >> 3;
  const int bid   = (int)blockIdx.x;
  int sbid = (bid & 7) * chunk + (bid >> 3);
  const int pb = ntm * ntn;
  const int z  = sbid / pb;  sbid -= z * pb;
  const int mt = sbid / ntn;
  const int nt = sbid - mt * ntn;
  const int m0 = mt * 256, n0 = nt * 256;

  const bf16* A = Ap + (size_t)z * sA;
  const bf16* B = Bp + (size_t)z * sB;

  // staging map: row sr (0..63 per segment), chunk sc8; global chunk pre-swizzled
  const int sr  = tid >> 3;
  const int sc8 = tid & 7;
  const int gch = sc8 ^ (sr & 7);
  const bf16* Ast = A + (size_t)(m0 + sr) * lda + gch * 8;
  const bf16* Bst = B + (size_t)(n0 + sr) * ldb + gch * 8;

  const int lr  = lane & 15;
  const int swz = (lane & 7) << 4;
  const int kb0 = (lane >> 4) * 16;

  f32x4 acc[8][4] = {};

  // prologue: stage K-tile 0, drain OWN loads, then barrier (publishes all)
  #pragma unroll
  for (int p = 0; p < 4; ++p) {
    gld_lds16(Ast + (size_t)(p * 64) * lda, &LDSB[0][p * 4096 + wv * 512]);
    gld_lds16(Bst + (size_t)(p * 64) * ldb, &LDSB[2][p * 4096 + wv * 512]);
  }
  asm volatile("s_waitcnt vmcnt(0)" ::: "memory");
  __builtin_amdgcn_s_barrier();
  __builtin_amdgcn_sched_barrier(0);

  const int nkt = K >> 6;
  for (int t = 0; t < nkt; ++t) {
    const int cur = t & 1;
    const bf16* Acur = LDSB[cur];
    const bf16* Bcur = LDSB[2 + cur];
    bf16* Asn = LDSB[cur ^ 1];
    bf16* Bsn = LDSB[2 + (cur ^ 1)];
    const int ktn = (t + 1) << 6;
    bf16x8 af[4][2];
    PHASE(0, 0, 1, STAGE2(0, 1));   // stages get ~3 phases of compute cover
    PHASE(0, 1, 0, STAGE2(2, 3));
    PHASE(1, 1, 1, ;);
    PHASE(1, 0, 0, ;);
    asm volatile("s_waitcnt vmcnt(0)" ::: "memory"); // drain OWN stages FIRST
    __builtin_amdgcn_s_barrier();                    // then publish to all waves
    __builtin_amdgcn_sched_barrier(0);
  }

  // epilogue: C/D layout col=lane&15, row=(lane>>4)*4+reg (m89-verified)
  if (TR_V && nt >= 6) {
    // V block: write transposed to VT via LDS (row-major qkv store skipped)
    bf16* tile = LDSB[0];   // 256 c-rows x 512 B, XOR-swizzled; uses all 128 KiB
    __syncthreads();
    #pragma unroll
    for (int mf = 0; mf < 8; ++mf) {
      #pragma unroll
      for (int nf = 0; nf < 4; ++nf) {
        const int lm = wm * 128 + mf * 16 + (lane >> 4) * 4; // 4 consecutive m
        const int lc = wn * 64 + nf * 16 + (lane & 15);      // c within tile
        bf16x4 w;
        #pragma unroll
        for (int r = 0; r < 4; ++r) {
          float v = acc[mf][nf][r] * scale;
          if (HAS_BIAS) v += bias[n0 + lc];
          w[r] = (bf16)v;
        }
        *(bf16x4*)((char*)tile + lc * 512 + ((lm * 2) ^ ((lc & 7) << 4))) = w;
      }
    }
    __syncthreads();
    const int bz = m0 >> 10;          // batch index (256-row tile within one batch)
    const int mb = m0 & 1023;
    bf16* dst = vtout + ((size_t)bz * CDIM + (n0 - 2 * CDIM)) * SEQ + mb;
    #pragma unroll
    for (int it = 0; it < 16; ++it) {
      const int c  = (tid >> 5) + it * 16;
      const int ch = tid & 31;
      bf16x8 vv = *(const bf16x8*)((const char*)tile + c * 512 + ((ch * 16) ^ ((c & 7) << 4)));
      *(bf16x8*)(dst + (size_t)c * SEQ + ch * 8) = vv;
    }
  } else if (FUSE_EXP) {
    float rs[8][4];
    #pragma unroll
    for (int mf = 0; mf < 8; ++mf)
      #pragma unroll
      for (int r = 0; r < 4; ++r) rs[mf][r] = 0.f;
    #pragma unroll
    for (int mf = 0; mf < 8; ++mf)
      #pragma unroll
      for (int nf = 0; nf < 4; ++nf)
        #pragma unroll
        for (int r = 0; r < 4; ++r) {
          int gm = m0 + wm * 128 + mf * 16 + ((lane >> 4) * 4 + r);
          int gn = n0 + wn * 64 + nf * 16 + (lane & 15);
          float e = __expf(acc[mf][nf][r] * scale);
          ((bf16*)Cp)[(size_t)z * sC + (size_t)gm * ldc + gn] = (bf16)e;
          rs[mf][r] += e;
        }
    float* sl = (float*)LDSB;  // [4 strips][256 rows], LDS free after K-loop
    #pragma unroll
    for (int mf = 0; mf < 8; ++mf)
      #pragma unroll
      for (int r = 0; r < 4; ++r) {
        float s = rs[mf][r];
        s += __shfl_xor(s, 1); s += __shfl_xor(s, 2);
        s += __shfl_xor(s, 4); s += __shfl_xor(s, 8);
        if ((lane & 15) == 0)
          sl[wn * 256 + wm * 128 + mf * 16 + (lane >> 4) * 4 + r] = s;
      }
    __syncthreads();
    if (tid < 256) {
      float s = sl[tid] + sl[256 + tid] + sl[512 + tid] + sl[768 + tid];
      partial[((size_t)z * SEQ + m0 + tid) * 4 + nt] = s;
    }
  } else {
    #pragma unroll
    for (int mf = 0; mf < 8; ++mf) {
      #pragma unroll
      for (int nf = 0; nf < 4; ++nf) {
        #pragma unroll
        for (int r = 0; r < 4; ++r) {
          int gm = m0 + wm * 128 + mf * 16 + ((lane >> 4) * 4 + r);
          int gn = n0 + wn * 64 + nf * 16 + (lane & 15);
          float v = acc[mf][nf][r] * scale;
          if (ROW_SCALE) v *= rowScale[(size_t)z * sRS + gm];
          if (HAS_BIAS)  v += bias[gn];
          if (OUT_BF16) ((bf16*)Cp)[(size_t)z * sC + (size_t)gm * ldc + gn] = (bf16)v;
          else          ((float*)Cp)[(size_t)z * sC + (size_t)gm * ldc + gn] = v;
        }
      }
    }
  }
}

extern "C" void kernel_launch(void* const* d_in, const int* in_sizes, int n_in,
                              void* d_out, int out_size, void* d_ws, size_t ws_size,
                              hipStream_t stream) {
  const float* x     = (const float*)d_in[0];
  const float* Wqkv  = (const float*)d_in[1];
  const float* bqkv  = (const float*)d_in[2];
  const float* Wproj = (const float*)d_in[3];
  const float* bproj = (const float*)d_in[4];
  float* out = (float*)d_out;
  char*  ws  = (char*)d_ws;

  bf16*  WqT = (bf16*)(ws + oWqT);
  bf16*  WpT = (bf16*)(ws + oWpT);
  bf16*  qkv = (bf16*)(ws + oQKV);
  bf16*  S   = (bf16*)(ws + oS);
  bf16*  VT  = (bf16*)(ws + oVT);
  float* inv = (float*)(ws + oInv);
  bf16*  AO  = (bf16*)(ws + oAO);
  bf16*  xb  = (bf16*)(ws + oXB);
  float* part= (float*)(ws + oPart);

  const float qk_scale = 1.0f / sqrtf((float)CDIM);

  // 1. conversions / transposes
  f2b_kernel<<<ROWS * CDIM / 8 / 256, 256, 0, stream>>>(x, xb);
  wt_kernel<<<dim3(768 / 32, QKVC / 32), 256, 0, stream>>>(Wqkv, WqT, QKVC);
  wt_kernel<<<dim3(768 / 32, CDIM / 32), 256, 0, stream>>>(Wproj, WpT, CDIM);

  // 2. qkv = xb @ WqT^T + b_qkv; V third written transposed to VT (TR_V)
  gemm256<true, true, false, false, true><<<(ROWS / 256) * (QKVC / 256), 512, 0, stream>>>(
      xb, WqT, qkv, CDIM, CDIM, CDIM, QKVC, ROWS / 256, QKVC / 256,
      0, 0, 0, 1.0f, nullptr, 0, bqkv, nullptr, VT);

  // 3. S = exp(q @ k^T * scale), fused row-partial sums (overwrites xb & WqT — both dead)
  gemm256<true, false, false, true, false><<<BATCH * (SEQ / 256) * (SEQ / 256), 512, 0, stream>>>(
      qkv, qkv + CDIM, S, CDIM, QKVC, QKVC, SEQ, SEQ / 256, SEQ / 256,
      (long)SEQ * QKVC, (long)SEQ * QKVC, (long)SEQ * SEQ, qk_scale, nullptr, 0, nullptr, part, nullptr);

  // 4. inv = 1/rowsum  (sums the 4 n-tile partials)
  finish_kernel<<<ROWS / 256, 256, 0, stream>>>(part, inv);

  // 5. attn_out = (expS @ VT^T) * inv[row]   [32 x 1024 x 768]
  gemm256<true, false, true, false, false><<<BATCH * (SEQ / 256) * (CDIM / 256), 512, 0, stream>>>(
      S, VT, AO, SEQ, SEQ, SEQ, CDIM, SEQ / 256, CDIM / 256,
      (long)SEQ * SEQ, (long)CDIM * SEQ, (long)SEQ * CDIM, 1.0f, inv, SEQ, nullptr, nullptr, nullptr);

  // 6. out = attn_out @ WpT^T + b_proj   [32768 x 768], fp32
  gemm256<false, true, false, false, false><<<(ROWS / 256) * (CDIM / 256), 512, 0, stream>>>(
      AO, WpT, out, CDIM, CDIM, CDIM, CDIM, ROWS / 256, CDIM / 256,
      0, 0, 0, 1.0f, nullptr, 0, bproj, nullptr, nullptr);
}